// Round 2
// baseline (490.427 us; speedup 1.0000x reference)
//
#include <hip/hip_runtime.h>

#define BETA 0.9f
#define THRESH 1.0f

constexpr int Bsz  = 64;
constexpr int Din  = 1024;
constexpr int Dout = 1024;
constexpr int NBJ  = Bsz * Dout;        // 65536

// clang-native 4-float vector: required by __builtin_nontemporal_store
// (HIP's float4 is a struct wrapper it won't accept).
typedef float f4 __attribute__((ext_vector_type(4)));

// ---------------------------------------------------------------------------
// A: fused GEMM + LIF elementwise.
// grid = Bsz * (Dout/64) = 1024 blocks x 256 threads (16 waves/CU).
// Block (b, jg) computes I[b, jg*64 .. +63]: wave w accumulates k-slice
// [w*256, w*256+256) (W reads are 256 B coalesced per wave, W is L2/L3
// resident), LDS tree-reduce across the 4 waves, then wave 0 applies the LIF
// elementwise math + E_b update and stashes one_m for kernel B.
// ---------------------------------------------------------------------------
__global__ __launch_bounds__(256) void gemm_lif(const float* __restrict__ x,
                                                const float* __restrict__ W,
                                                const float* __restrict__ bias,
                                                const float* __restrict__ u0,
                                                const float* __restrict__ E_b,
                                                float* __restrict__ out_spk,
                                                float* __restrict__ out_u,
                                                float* __restrict__ out_Eb,
                                                float* __restrict__ one_m_ws) {
    __shared__ float red[4][64];        // [k-slice][j] — write 64-consec/wave,
                                        // read stride-64: both conflict-free
    const int blk = blockIdx.x;
    const int b   = blk >> 4;           // sample 0..63
    const int jg  = blk & 15;           // 64-column group
    const int t   = threadIdx.x;
    const int jl  = t & 63;             // column within group
    const int ks  = t >> 6;             // k-slice == wave id
    const int j   = (jg << 6) + jl;

    const float* xr = x + b * Din + (ks << 8);
    const float* Wc = W + (size_t)(ks << 8) * Dout + j;

    float acc = 0.f;
#pragma unroll 16
    for (int k = 0; k < 256; ++k)
        acc = fmaf(xr[k], Wc[(size_t)k * Dout], acc);

    red[ks][jl] = acc;
    __syncthreads();

    if (t < 64) {                       // jl == t here, so j = jg*64 + t
        const int idx = b * Dout + j;
        float I   = red[0][t] + red[1][t] + red[2][t] + red[3][t] + bias[j];
        float v   = fmaf(BETA, u0[idx], I);
        float vt  = v - THRESH;
        float spk = vt > 0.f ? 1.f : 0.f;
        float a   = 1.f + fabsf(vt);
        float om  = 1.f - THRESH / (a * a);   // one_m = 1 - THRESH*sg

        out_spk[idx]  = spk;
        out_u[idx]    = v - THRESH * spk;     // soft reset
        // E_b_new = BETA*one_m*E_b + one_m = one_m*(BETA*E_b + 1)
        out_Eb[idx]   = om * fmaf(BETA, E_b[idx], 1.f);
        one_m_ws[idx] = om;
    }
}

// ---------------------------------------------------------------------------
// B: the 512 MB E_W stream.  E_W_new[b,i,j] = one_m[b,j]*(BETA*E_W[b,i,j]+x[b,i])
// grid = 4096 blocks x 256 threads (16 blocks/CU), 16 float4 per thread.
// Block (b, 16-row band): thread tid owns column-vec4 jv=tid for 16 consecutive
// rows i. one_m is loaded ONCE per thread (was: once per vec4 = 16x more),
// x-row scalars are block-uniform (scalar cache), E_W load/store stay fully
// coalesced at 16 B/lane. Non-temporal stores keep the write-once output from
// evicting the not-yet-read E_W input out of L2/L3.
// ---------------------------------------------------------------------------
__global__ __launch_bounds__(256) void ew_update(const float* __restrict__ E_W,
                                                 const float* __restrict__ x,
                                                 const float* __restrict__ one_m,
                                                 float* __restrict__ out_EW) {
    const int blk = blockIdx.x;
    const int b   = blk >> 6;            // 64 blocks per sample
    const int i0  = (blk & 63) << 4;     // first of this block's 16 rows
    const int tid = threadIdx.x;

    const f4 om = ((const f4*)one_m)[(b << 8) + tid];          // reused 16x
    const float* xr = x + (b << 10) + i0;                      // uniform scalars
    const f4* __restrict__ src = (const f4*)E_W + (size_t)blk * 4096 + tid;
    f4* __restrict__       dst = (f4*)out_EW    + (size_t)blk * 4096 + tid;

#pragma unroll
    for (int it = 0; it < 16; ++it) {
        const float xs = xr[it];
        const f4    e  = src[it * 256];
        f4 r;
        r.x = om.x * fmaf(BETA, e.x, xs);
        r.y = om.y * fmaf(BETA, e.y, xs);
        r.z = om.z * fmaf(BETA, e.z, xs);
        r.w = om.w * fmaf(BETA, e.w, xs);
        __builtin_nontemporal_store(r, &dst[it * 256]);
    }
}

extern "C" void kernel_launch(void* const* d_in, const int* in_sizes, int n_in,
                              void* d_out, int out_size, void* d_ws, size_t ws_size,
                              hipStream_t stream) {
    const float* x    = (const float*)d_in[0];
    const float* W    = (const float*)d_in[1];
    const float* bias = (const float*)d_in[2];
    const float* u0   = (const float*)d_in[3];
    const float* E_W  = (const float*)d_in[4];
    const float* E_b  = (const float*)d_in[5];

    float* out     = (float*)d_out;
    float* out_spk = out;                       // [64,1024]
    float* out_u   = out + NBJ;                 // [64,1024]
    float* out_EW  = out + 2 * NBJ;             // [64,1024,1024]
    float* out_Eb  = out + 2 * NBJ + (size_t)Bsz * Din * Dout;  // [64,1024]

    float* one_m = (float*)d_ws;                // 256 KB

    gemm_lif<<<Bsz * (Dout / 64), 256, 0, stream>>>(x, W, bias, u0, E_b,
                                                    out_spk, out_u, out_Eb, one_m);
    ew_update<<<Bsz * (Din / 16), 256, 0, stream>>>(E_W, x, one_m, out_EW);
}